// Round 1
// baseline (257.912 us; speedup 1.0000x reference)
//
#include <hip/hip_runtime.h>
#include <hip/hip_bf16.h>

#define NN 8192
#define EE 262144
#define EP (EE + NN)      // 270336 edges incl. self loops
#define FDIM 256          // HEADS*OUT

typedef __attribute__((ext_vector_type(8))) short bf16x8;
typedef __attribute__((ext_vector_type(16))) float f32x16;

__device__ inline float wred_sum(float v){
#pragma unroll
  for (int o = 32; o; o >>= 1) v += __shfl_xor(v, o, 64);
  return v;
}
__device__ inline float wred_max(float v){
#pragma unroll
  for (int o = 32; o; o >>= 1) v = fmaxf(v, __shfl_xor(v, o, 64));
  return v;
}

// ---------------- CSR build ----------------
__global__ void k_count(const int* __restrict__ ei, int* __restrict__ cnt){
  int i = blockIdx.x * blockDim.x + threadIdx.x;
  if (i >= EP) return;
  int dst = (i < EE) ? ei[EE + i] : (i - EE);
  atomicAdd(&cnt[dst], 1);
}

__global__ __launch_bounds__(1024) void k_scan(const int* __restrict__ cnt,
                                               int* __restrict__ row_ptr){
  __shared__ int part[1024];
  int t = threadIdx.x;
  int v[8]; int s = 0;
#pragma unroll
  for (int j = 0; j < 8; ++j){ v[j] = cnt[t * 8 + j]; s += v[j]; }
  part[t] = s;
  __syncthreads();
  for (int off = 1; off < 1024; off <<= 1){
    int x = (t >= off) ? part[t - off] : 0;
    __syncthreads();
    part[t] += x;
    __syncthreads();
  }
  int base = (t == 0) ? 0 : part[t - 1];
#pragma unroll
  for (int j = 0; j < 8; ++j){ row_ptr[t * 8 + j] = base; base += v[j]; }
  if (t == 1023) row_ptr[8192] = base;
}

__global__ void k_scatter(const int* __restrict__ ei, const int* __restrict__ row_ptr,
                          int* __restrict__ cur, int* __restrict__ csr_src){
  int i = blockIdx.x * blockDim.x + threadIdx.x;
  if (i >= EP) return;
  int src, dst;
  if (i < EE){ src = ei[i]; dst = ei[EE + i]; } else { src = dst = i - EE; }
  int pos = row_ptr[dst] + atomicAdd(&cur[dst], 1);
  csr_src[pos] = src;
}

// ---------------- attention logits al_s/al_d per node,head ----------------
__global__ void k_al(const float* __restrict__ h, const float* __restrict__ as_att,
                     const float* __restrict__ ad_att, float* __restrict__ als,
                     float* __restrict__ ald){
  int w = (blockIdx.x * blockDim.x + threadIdx.x) >> 6;
  int lane = threadIdx.x & 63;
  if (w >= NN) return;
#pragma unroll
  for (int hh = 0; hh < 4; ++hh){
    float x = h[w * FDIM + hh * 64 + lane];
    float ps = x * as_att[hh * 64 + lane];
    float pd = x * ad_att[hh * 64 + lane];
    ps = wred_sum(ps);
    pd = wred_sum(pd);
    if (lane == 0){ als[w * 4 + hh] = ps; ald[w * 4 + hh] = pd; }
  }
}

// ---------------- GAT aggregation: one wave per (node, head) ----------------
template <bool RELU_BIAS>
__global__ void k_gat(const float* __restrict__ hfeat, const float* __restrict__ als,
                      const float* __restrict__ ald, const int* __restrict__ row_ptr,
                      const int* __restrict__ csr_src, const float* __restrict__ bias,
                      float* __restrict__ out){
  int w = (blockIdx.x * blockDim.x + threadIdx.x) >> 6;
  int lane = threadIdx.x & 63;
  if (w >= NN * 4) return;
  int n = w >> 2, hh = w & 3;
  int b0 = row_ptr[n], e0 = row_ptr[n + 1];
  float ad = ald[n * 4 + hh];

  // pass 1: exact segment max
  float m = -1e30f;
  for (int c = b0; c < e0; c += 64){
    int j = c + lane;
    float ev = -1e30f;
    if (j < e0){
      int s = csr_src[j];
      float as_ = als[s * 4 + hh];
      ev = as_ + ad;
      ev = ev > 0.f ? ev : 0.2f * ev;
    }
    m = fmaxf(m, ev);
  }
  m = wred_max(m);

  // pass 2: exp, denom, weighted feature gather
  float den = 0.f, acc = 0.f;
  for (int c = b0; c < e0; c += 64){
    int j = c + lane;
    int sv = 0; float pv = 0.f;
    if (j < e0){
      sv = csr_src[j];
      float as_ = als[sv * 4 + hh];
      float ev = as_ + ad;
      ev = ev > 0.f ? ev : 0.2f * ev;
      pv = __expf(ev - m);
    }
    den += pv;
    int cnt = min(64, e0 - c);
    for (int jj = 0; jj < cnt; ++jj){
      int s = __shfl(sv, jj, 64);
      float p = __shfl(pv, jj, 64);
      acc = fmaf(p, hfeat[s * FDIM + hh * 64 + lane], acc);
    }
  }
  den = wred_sum(den);
  float o = acc / (den + 1e-16f);
  if (RELU_BIAS){
    o = fmaxf(o + bias[hh * 64 + lane], 0.f);
  }
  out[n * FDIM + hh * 64 + lane] = o;
}

// ---------------- h2 = hrelu @ W2  (8192x256x256 f32) ----------------
__global__ __launch_bounds__(256) void k_gemm2(const float* __restrict__ hrelu,
                                               const float* __restrict__ W2,
                                               float* __restrict__ h2){
  __shared__ float hs[16 * 256];
  int bn = blockIdx.x * 16;
  int tid = threadIdx.x;
  for (int idx = tid; idx < 16 * 256; idx += 256) hs[idx] = hrelu[bn * FDIM + idx];
  __syncthreads();
  int jg = tid & 63, ng = tid >> 6;
  float acc[4][4];
#pragma unroll
  for (int i = 0; i < 4; ++i)
#pragma unroll
    for (int c = 0; c < 4; ++c) acc[i][c] = 0.f;
  for (int k = 0; k < 256; ++k){
    float4 wv = *reinterpret_cast<const float4*>(W2 + k * 256 + 4 * jg);
#pragma unroll
    for (int i = 0; i < 4; ++i){
      float hv = hs[(4 * ng + i) * 256 + k];
      acc[i][0] = fmaf(hv, wv.x, acc[i][0]);
      acc[i][1] = fmaf(hv, wv.y, acc[i][1]);
      acc[i][2] = fmaf(hv, wv.z, acc[i][2]);
      acc[i][3] = fmaf(hv, wv.w, acc[i][3]);
    }
  }
#pragma unroll
  for (int i = 0; i < 4; ++i){
    float4 r; r.x = acc[i][0]; r.y = acc[i][1]; r.z = acc[i][2]; r.w = acc[i][3];
    *reinterpret_cast<float4*>(h2 + (bn + 4 * ng + i) * FDIM + 4 * jg) = r;
  }
}

// ---------------- z = tanh(mean_h(out2h) + b2); also bf16 copy ----------------
__global__ void k_z(const float* __restrict__ out2h, const float* __restrict__ b2,
                    float* __restrict__ zout, ushort* __restrict__ zb){
  int i = blockIdx.x * blockDim.x + threadIdx.x;
  if (i >= NN * 64) return;
  int n = i >> 6, f = i & 63;
  float s = 0.f;
#pragma unroll
  for (int hh = 0; hh < 4; ++hh) s += out2h[n * FDIM + hh * 64 + f];
  float v = tanhf(0.25f * s + b2[f]);
  zout[i] = v;
  __hip_bfloat16 bb = __float2bfloat16(v);
  zb[i] = *reinterpret_cast<ushort*>(&bb);
}

// ---------------- adj = sigmoid(z z^T) via bf16 MFMA ----------------
__global__ __launch_bounds__(256) void k_adj(const ushort* __restrict__ zb,
                                             float* __restrict__ adj){
  int wid = threadIdx.x >> 6, lane = threadIdx.x & 63;
  int wr = wid >> 1, wc = wid & 1;           // 2x2 waves, each 64x64 tile
  int row0 = blockIdx.y * 128 + wr * 64;
  int col0 = blockIdx.x * 128 + wc * 64;
  int r = lane & 31, half = lane >> 5;

  bf16x8 a[2][4], b[2][4];
#pragma unroll
  for (int i = 0; i < 2; ++i)
#pragma unroll
    for (int kc = 0; kc < 4; ++kc){
      a[i][kc] = *reinterpret_cast<const bf16x8*>(zb + (size_t)(row0 + 32 * i + r) * 64 + kc * 16 + 8 * half);
      b[i][kc] = *reinterpret_cast<const bf16x8*>(zb + (size_t)(col0 + 32 * i + r) * 64 + kc * 16 + 8 * half);
    }

  f32x16 c[2][2];
#pragma unroll
  for (int i = 0; i < 2; ++i)
#pragma unroll
    for (int j = 0; j < 2; ++j)
#pragma unroll
      for (int t = 0; t < 16; ++t) c[i][j][t] = 0.f;

#pragma unroll
  for (int kc = 0; kc < 4; ++kc)
#pragma unroll
    for (int i = 0; i < 2; ++i)
#pragma unroll
      for (int j = 0; j < 2; ++j)
        c[i][j] = __builtin_amdgcn_mfma_f32_32x32x16_bf16(a[i][kc], b[j][kc], c[i][j], 0, 0, 0);

#pragma unroll
  for (int i = 0; i < 2; ++i)
#pragma unroll
    for (int j = 0; j < 2; ++j)
#pragma unroll
      for (int t = 0; t < 16; ++t){
        int rr = (t & 3) + 8 * (t >> 2) + 4 * half;
        size_t row = row0 + 32 * i + rr;
        size_t col = col0 + 32 * j + (lane & 31);
        float v = c[i][j][t];
        adj[row * NN + col] = 1.0f / (1.0f + __expf(-v));
      }
}

extern "C" void kernel_launch(void* const* d_in, const int* in_sizes, int n_in,
                              void* d_out, int out_size, void* d_ws, size_t ws_size,
                              hipStream_t stream){
  (void)in_sizes; (void)n_in; (void)out_size; (void)ws_size;
  const int*   ei  = (const int*)d_in[1];
  const float* W1  = (const float*)d_in[2];
  const float* as1 = (const float*)d_in[3];
  const float* ad1 = (const float*)d_in[4];
  const float* b1  = (const float*)d_in[5];
  const float* W2  = (const float*)d_in[6];
  const float* as2 = (const float*)d_in[7];
  const float* ad2 = (const float*)d_in[8];
  const float* b2  = (const float*)d_in[9];

  char* ws = (char*)d_ws;
  float* hrelu = (float*)(ws + 0);                   // 8 MB
  float* h2    = (float*)(ws + (8u  << 20));         // 8 MB
  float* out2h = (float*)(ws + (16u << 20));         // 8 MB
  float* al1s  = (float*)(ws + (24u << 20));
  float* al1d  = al1s + NN * 4;
  float* al2s  = al1d + NN * 4;
  float* al2d  = al2s + NN * 4;
  int* cnt     = (int*)(ws + (25u << 20));           // 64 KB slot
  int* cur     = cnt + 16384;
  int* row_ptr = cur + 16384;
  int* csr_src = row_ptr + 16384;                    // 1.06 MB used
  ushort* zb   = (ushort*)(ws + (27u << 20));        // 1 MB

  float* adj  = (float*)d_out;
  float* zout = adj + (size_t)NN * NN;

  hipMemsetAsync(cnt, 0, 2 * 16384 * sizeof(int), stream);
  k_count<<<(EP + 255) / 256, 256, 0, stream>>>(ei, cnt);
  k_scan<<<1, 1024, 0, stream>>>(cnt, row_ptr);
  k_scatter<<<(EP + 255) / 256, 256, 0, stream>>>(ei, row_ptr, cur, csr_src);

  // layer 1 (h1 = W1 because x == I)
  k_al<<<NN * 64 / 256, 256, 0, stream>>>(W1, as1, ad1, al1s, al1d);
  k_gat<true><<<NN * 4 * 64 / 256, 256, 0, stream>>>(W1, al1s, al1d, row_ptr, csr_src, b1, hrelu);

  // layer 2
  k_gemm2<<<NN / 16, 256, 0, stream>>>(hrelu, W2, h2);
  k_al<<<NN * 64 / 256, 256, 0, stream>>>(h2, as2, ad2, al2s, al2d);
  k_gat<false><<<NN * 4 * 64 / 256, 256, 0, stream>>>(h2, al2s, al2d, row_ptr, csr_src, nullptr, out2h);

  // z and adjacency reconstruction
  k_z<<<NN * 64 / 256, 256, 0, stream>>>(out2h, b2, zout, zb);
  dim3 g(NN / 128, NN / 128);
  k_adj<<<g, 256, 0, stream>>>(zb, adj);
}

// Round 3
// 159.477 us; speedup vs baseline: 1.6172x; 1.6172x over previous
//
#include <hip/hip_runtime.h>
#include <hip/hip_bf16.h>

#define NN 8192
#define EE 262144
#define EP (EE + NN)      // edges incl. self loops
#define FDIM 256          // HEADS*OUT

typedef __attribute__((ext_vector_type(4)))  short bf16x4;
typedef __attribute__((ext_vector_type(8)))  short bf16x8;
typedef __attribute__((ext_vector_type(16))) float f32x16;

__device__ inline float bf2f(short u){
  return __builtin_bit_cast(float, ((unsigned)(unsigned short)u) << 16);
}
__device__ inline unsigned short f2bf(float f){
  __hip_bfloat16 b = __float2bfloat16(f);
  return __builtin_bit_cast(unsigned short, b);
}
__device__ inline float wred_sum(float v){
#pragma unroll
  for (int o = 32; o; o >>= 1) v += __shfl_xor(v, o, 64);
  return v;
}

// ---------------- converts ----------------
__global__ void k_cvt(const float* __restrict__ in, unsigned short* __restrict__ out, int n4){
  int i = blockIdx.x * blockDim.x + threadIdx.x;
  if (i >= n4) return;
  float4 v = reinterpret_cast<const float4*>(in)[i];
  uint2 p;
  p.x = (unsigned)f2bf(v.x) | ((unsigned)f2bf(v.y) << 16);
  p.y = (unsigned)f2bf(v.z) | ((unsigned)f2bf(v.w) << 16);
  reinterpret_cast<uint2*>(out)[i] = p;
}

__global__ void k_w2t(const float* __restrict__ W2, unsigned short* __restrict__ W2t){
  int idx = blockIdx.x * blockDim.x + threadIdx.x;   // 65536
  int j = idx >> 8, k = idx & 255;
  W2t[idx] = f2bf(W2[k * 256 + j]);
}

// ---------------- CSR build ----------------
__global__ void k_count(const int* __restrict__ ei, int* __restrict__ cnt){
  int i = blockIdx.x * blockDim.x + threadIdx.x;
  if (i >= EP) return;
  int dst = (i < EE) ? ei[EE + i] : (i - EE);
  atomicAdd(&cnt[dst], 1);
}

__global__ __launch_bounds__(1024) void k_scan(const int* __restrict__ cnt,
                                               int* __restrict__ row_ptr){
  __shared__ int part[1024];
  int t = threadIdx.x;
  int v[8]; int s = 0;
#pragma unroll
  for (int j = 0; j < 8; ++j){ v[j] = cnt[t * 8 + j]; s += v[j]; }
  part[t] = s;
  __syncthreads();
  for (int off = 1; off < 1024; off <<= 1){
    int x = (t >= off) ? part[t - off] : 0;
    __syncthreads();
    part[t] += x;
    __syncthreads();
  }
  int base = (t == 0) ? 0 : part[t - 1];
#pragma unroll
  for (int j = 0; j < 8; ++j){ row_ptr[t * 8 + j] = base; base += v[j]; }
  if (t == 1023) row_ptr[8192] = base;
}

__global__ void k_scatter(const int* __restrict__ ei, const int* __restrict__ row_ptr,
                          int* __restrict__ cur, int* __restrict__ csr_src){
  int i = blockIdx.x * blockDim.x + threadIdx.x;
  if (i >= EP) return;
  int src, dst;
  if (i < EE){ src = ei[i]; dst = ei[EE + i]; } else { src = dst = i - EE; }
  int pos = row_ptr[dst] + atomicAdd(&cur[dst], 1);
  csr_src[pos] = src;
}

// ---------------- attention logits per (node,head): wave per node ----------------
__global__ void k_al_b(const unsigned short* __restrict__ hb, const float* __restrict__ as_att,
                       const float* __restrict__ ad_att, float* __restrict__ als,
                       float* __restrict__ ald){
  int w = (blockIdx.x * blockDim.x + threadIdx.x) >> 6;   // node
  int lane = threadIdx.x & 63;
  if (w >= NN) return;
  int f = lane << 2;
  bf16x4 hv = *reinterpret_cast<const bf16x4*>(hb + w * FDIM + f);
  float4 as4 = *reinterpret_cast<const float4*>(as_att + f);
  float4 ad4 = *reinterpret_cast<const float4*>(ad_att + f);
  float x0 = bf2f(hv[0]), x1 = bf2f(hv[1]), x2 = bf2f(hv[2]), x3 = bf2f(hv[3]);
  float ps = fmaf(x0, as4.x, fmaf(x1, as4.y, fmaf(x2, as4.z, x3 * as4.w)));
  float pd = fmaf(x0, ad4.x, fmaf(x1, ad4.y, fmaf(x2, ad4.z, x3 * ad4.w)));
#pragma unroll
  for (int o = 1; o < 16; o <<= 1){ ps += __shfl_xor(ps, o, 64); pd += __shfl_xor(pd, o, 64); }
  if ((lane & 15) == 0){
    int hh = lane >> 4;
    als[w * 4 + hh] = ps;
    ald[w * 4 + hh] = pd;
  }
}

// ---------------- softmax numerators + 1/denominator: wave per (node,head) ----------
__global__ void k_softmax(const float* __restrict__ als, const float* __restrict__ ald,
                          const int* __restrict__ row_ptr, const int* __restrict__ csr_src,
                          float* __restrict__ alpha, float* __restrict__ rden){
  int w = (blockIdx.x * blockDim.x + threadIdx.x) >> 6;
  int lane = threadIdx.x & 63;
  if (w >= NN * 4) return;
  int n = w >> 2, hh = w & 3;
  int b0 = row_ptr[n], e0 = row_ptr[n + 1];
  float ad = ald[n * 4 + hh];
  float den = 0.f;
  for (int c = b0; c < e0; c += 64){
    int j = c + lane;
    if (j < e0){
      int s = csr_src[j];
      float ev = als[s * 4 + hh] + ad;
      ev = ev > 0.f ? ev : 0.2f * ev;      // leaky_relu(0.2)
      float pv = __expf(ev);               // |ev| small: no max-subtraction needed
      alpha[j * 4 + hh] = pv;
      den += pv;
    }
  }
  den = wred_sum(den);
  if (lane == 0) rden[n * 4 + hh] = 1.f / (den + 1e-16f);
}

// ---------------- aggregation: wave per node, lane owns 4 features ----------------
template <bool L1>
__global__ __launch_bounds__(256) void k_agg(const unsigned short* __restrict__ hb,
                                             const float* __restrict__ alpha,
                                             const float* __restrict__ rden,
                                             const int* __restrict__ row_ptr,
                                             const int* __restrict__ csr_src,
                                             const float* __restrict__ bias,
                                             float* __restrict__ outf,
                                             unsigned short* __restrict__ outb){
  int wid = threadIdx.x >> 6, lane = threadIdx.x & 63;
  int n = blockIdx.x * 4 + wid;
  int b0 = row_ptr[n], e0 = row_ptr[n + 1];
  int hh = lane >> 4;
  int f = lane << 2;
  float a0 = 0.f, a1 = 0.f, a2 = 0.f, a3 = 0.f;
  const unsigned short* hp = hb + f;
#pragma unroll 4
  for (int c = b0; c < e0; ++c){
    int s = csr_src[c];                          // uniform within wave
    float a = alpha[c * 4 + hh];
    bf16x4 hv = *reinterpret_cast<const bf16x4*>(hp + s * FDIM);
    a0 = fmaf(a, bf2f(hv[0]), a0);
    a1 = fmaf(a, bf2f(hv[1]), a1);
    a2 = fmaf(a, bf2f(hv[2]), a2);
    a3 = fmaf(a, bf2f(hv[3]), a3);
  }
  float r = rden[n * 4 + hh];
  if (L1){
    float4 bv = *reinterpret_cast<const float4*>(bias + f);
    float o0 = fmaxf(fmaf(a0, r, bv.x), 0.f);
    float o1 = fmaxf(fmaf(a1, r, bv.y), 0.f);
    float o2 = fmaxf(fmaf(a2, r, bv.z), 0.f);
    float o3 = fmaxf(fmaf(a3, r, bv.w), 0.f);
    uint2 p;
    p.x = (unsigned)f2bf(o0) | ((unsigned)f2bf(o1) << 16);
    p.y = (unsigned)f2bf(o2) | ((unsigned)f2bf(o3) << 16);
    *reinterpret_cast<uint2*>(outb + n * FDIM + f) = p;
  } else {
    float4 o; o.x = a0 * r; o.y = a1 * r; o.z = a2 * r; o.w = a3 * r;
    *reinterpret_cast<float4*>(outf + n * FDIM + f) = o;
  }
}

// ---------------- h2 = hrelu @ W2 via bf16 MFMA ----------------
__global__ __launch_bounds__(256) void k_gemm2(const unsigned short* __restrict__ A,
                                               const unsigned short* __restrict__ Bt,
                                               unsigned short* __restrict__ Cb){
  int wid = threadIdx.x >> 6, lane = threadIdx.x & 63;
  int row0 = blockIdx.x * 128 + wid * 32;
  int col0 = blockIdx.y * 64;
  int r = lane & 31, half = lane >> 5;
  f32x16 acc0, acc1;
#pragma unroll
  for (int t = 0; t < 16; ++t){ acc0[t] = 0.f; acc1[t] = 0.f; }
#pragma unroll
  for (int k0 = 0; k0 < 256; k0 += 16){
    bf16x8 av  = *reinterpret_cast<const bf16x8*>(A  + (row0 + r)      * 256 + k0 + 8 * half);
    bf16x8 b0v = *reinterpret_cast<const bf16x8*>(Bt + (col0 + r)      * 256 + k0 + 8 * half);
    bf16x8 b1v = *reinterpret_cast<const bf16x8*>(Bt + (col0 + 32 + r) * 256 + k0 + 8 * half);
    acc0 = __builtin_amdgcn_mfma_f32_32x32x16_bf16(av, b0v, acc0, 0, 0, 0);
    acc1 = __builtin_amdgcn_mfma_f32_32x32x16_bf16(av, b1v, acc1, 0, 0, 0);
  }
#pragma unroll
  for (int t = 0; t < 16; ++t){
    int rr = (t & 3) + 8 * (t >> 2) + 4 * half;
    Cb[(row0 + rr) * 256 + col0 + r]      = f2bf(acc0[t]);
    Cb[(row0 + rr) * 256 + col0 + 32 + r] = f2bf(acc1[t]);
  }
}

// ---------------- z = tanh(mean_h + b2); f32 out + bf16 copy ----------------
__global__ void k_z(const float* __restrict__ out2h, const float* __restrict__ b2,
                    float* __restrict__ zout, unsigned short* __restrict__ zb){
  int i = blockIdx.x * blockDim.x + threadIdx.x;
  if (i >= NN * 64) return;
  int n = i >> 6, f = i & 63;
  float s = 0.f;
#pragma unroll
  for (int hh = 0; hh < 4; ++hh) s += out2h[n * FDIM + hh * 64 + f];
  float v = tanhf(0.25f * s + b2[f]);
  zout[i] = v;
  zb[i] = f2bf(v);
}

// ---------------- adj = sigmoid(z z^T) via bf16 MFMA ----------------
__global__ __launch_bounds__(256) void k_adj(const unsigned short* __restrict__ zb,
                                             float* __restrict__ adj){
  int wid = threadIdx.x >> 6, lane = threadIdx.x & 63;
  int wr = wid >> 1, wc = wid & 1;           // 2x2 waves, each 64x64 tile
  int row0 = blockIdx.y * 128 + wr * 64;
  int col0 = blockIdx.x * 128 + wc * 64;
  int r = lane & 31, half = lane >> 5;

  bf16x8 a[2][4], b[2][4];
#pragma unroll
  for (int i = 0; i < 2; ++i)
#pragma unroll
    for (int kc = 0; kc < 4; ++kc){
      a[i][kc] = *reinterpret_cast<const bf16x8*>(zb + (size_t)(row0 + 32 * i + r) * 64 + kc * 16 + 8 * half);
      b[i][kc] = *reinterpret_cast<const bf16x8*>(zb + (size_t)(col0 + 32 * i + r) * 64 + kc * 16 + 8 * half);
    }

  f32x16 c[2][2];
#pragma unroll
  for (int i = 0; i < 2; ++i)
#pragma unroll
    for (int j = 0; j < 2; ++j)
#pragma unroll
      for (int t = 0; t < 16; ++t) c[i][j][t] = 0.f;

#pragma unroll
  for (int kc = 0; kc < 4; ++kc)
#pragma unroll
    for (int i = 0; i < 2; ++i)
#pragma unroll
      for (int j = 0; j < 2; ++j)
        c[i][j] = __builtin_amdgcn_mfma_f32_32x32x16_bf16(a[i][kc], b[j][kc], c[i][j], 0, 0, 0);

#pragma unroll
  for (int i = 0; i < 2; ++i)
#pragma unroll
    for (int j = 0; j < 2; ++j)
#pragma unroll
      for (int t = 0; t < 16; ++t){
        int rr = (t & 3) + 8 * (t >> 2) + 4 * half;
        size_t row = row0 + 32 * i + rr;
        size_t col = col0 + 32 * j + (lane & 31);
        float v = c[i][j][t];
        adj[row * NN + col] = __builtin_amdgcn_rcpf(1.0f + __expf(-v));
      }
}

extern "C" void kernel_launch(void* const* d_in, const int* in_sizes, int n_in,
                              void* d_out, int out_size, void* d_ws, size_t ws_size,
                              hipStream_t stream){
  (void)in_sizes; (void)n_in; (void)out_size; (void)ws_size;
  const int*   ei  = (const int*)d_in[1];
  const float* W1  = (const float*)d_in[2];
  const float* as1 = (const float*)d_in[3];
  const float* ad1 = (const float*)d_in[4];
  const float* b1  = (const float*)d_in[5];
  const float* W2  = (const float*)d_in[6];
  const float* as2 = (const float*)d_in[7];
  const float* ad2 = (const float*)d_in[8];
  const float* b2  = (const float*)d_in[9];

  char* ws = (char*)d_ws;
  unsigned short* W1b    = (unsigned short*)(ws + 0);            // 4 MB
  unsigned short* hrelub = (unsigned short*)(ws + (4u  << 20));  // 4 MB
  unsigned short* h2b    = (unsigned short*)(ws + (8u  << 20));  // 4 MB
  float* out2h           = (float*)(ws + (12u << 20));           // 8 MB
  unsigned short* W2t    = (unsigned short*)(ws + (20u << 20));  // 128 KB
  float* als1            = (float*)(ws + (21u << 20));
  float* ald1            = als1 + NN * 4;
  float* als2            = ald1 + NN * 4;
  float* ald2            = als2 + NN * 4;
  float* rden1           = ald2 + NN * 4;
  float* rden2           = rden1 + NN * 4;
  float* alpha           = (float*)(ws + (22u << 20));           // 4.3 MB
  int* cnt               = (int*)(ws + (27u << 20));
  int* cur               = cnt + 16384;
  int* row_ptr           = cur + 16384;
  int* csr_src           = row_ptr + 16384;                      // 1.06 MB
  unsigned short* zb     = (unsigned short*)(ws + (30u << 20));  // 1 MB

  float* adj  = (float*)d_out;
  float* zout = adj + (size_t)NN * NN;

  // converts + CSR build
  hipMemsetAsync(cnt, 0, 2 * 16384 * sizeof(int), stream);
  k_cvt<<<(NN * FDIM / 4 + 255) / 256, 256, 0, stream>>>(W1, W1b, NN * FDIM / 4);
  k_w2t<<<65536 / 256, 256, 0, stream>>>(W2, W2t);
  k_count<<<(EP + 255) / 256, 256, 0, stream>>>(ei, cnt);
  k_scan<<<1, 1024, 0, stream>>>(cnt, row_ptr);
  k_scatter<<<(EP + 255) / 256, 256, 0, stream>>>(ei, row_ptr, cur, csr_src);

  // layer 1 (h1 = W1 because x == I)
  k_al_b<<<NN / 4, 256, 0, stream>>>(W1b, as1, ad1, als1, ald1);
  k_softmax<<<NN, 256, 0, stream>>>(als1, ald1, row_ptr, csr_src, alpha, rden1);
  k_agg<true><<<NN / 4, 256, 0, stream>>>(W1b, alpha, rden1, row_ptr, csr_src, b1, nullptr, hrelub);

  // layer 2
  dim3 gg(NN / 128, 4);   // FIX: all 256 output columns (was 2 -> heads 2,3 never computed)
  k_gemm2<<<gg, 256, 0, stream>>>(hrelub, W2t, h2b);
  k_al_b<<<NN / 4, 256, 0, stream>>>(h2b, as2, ad2, als2, ald2);
  k_softmax<<<NN, 256, 0, stream>>>(als2, ald2, row_ptr, csr_src, alpha, rden2);
  k_agg<false><<<NN / 4, 256, 0, stream>>>(h2b, alpha, rden2, row_ptr, csr_src, nullptr, out2h, nullptr);

  // z and adjacency reconstruction
  k_z<<<NN * 64 / 256, 256, 0, stream>>>(out2h, b2, zout, zb);
  dim3 g(NN / 128, NN / 128);
  k_adj<<<g, 256, 0, stream>>>(zb, adj);
}

// Round 4
// 133.345 us; speedup vs baseline: 1.9342x; 1.1960x over previous
//
#include <hip/hip_runtime.h>
#include <hip/hip_bf16.h>

#define NN 8192
#define EE 262144
#define EP (EE + NN)      // edges incl. self loops
#define FDIM 256          // HEADS*OUT

typedef __attribute__((ext_vector_type(4)))  short bf16x4;
typedef __attribute__((ext_vector_type(8)))  short bf16x8;
typedef __attribute__((ext_vector_type(16))) float f32x16;

__device__ inline float bf2f(short u){
  return __builtin_bit_cast(float, ((unsigned)(unsigned short)u) << 16);
}
__device__ inline unsigned short f2bf(float f){
  __hip_bfloat16 b = __float2bfloat16(f);
  return __builtin_bit_cast(unsigned short, b);
}

// ---------------- W1 bf16 convert + layer-1 attention logits (fused) ----------
__global__ __launch_bounds__(256) void k_cvt_al(const float* __restrict__ W1,
                                                const float* __restrict__ as_att,
                                                const float* __restrict__ ad_att,
                                                unsigned short* __restrict__ W1b,
                                                float* __restrict__ als,
                                                float* __restrict__ ald){
  int w = (blockIdx.x * blockDim.x + threadIdx.x) >> 6;   // node/row
  int lane = threadIdx.x & 63;
  int f = lane << 2;
  float4 v = *reinterpret_cast<const float4*>(W1 + w * FDIM + f);
  uint2 p;
  p.x = (unsigned)f2bf(v.x) | ((unsigned)f2bf(v.y) << 16);
  p.y = (unsigned)f2bf(v.z) | ((unsigned)f2bf(v.w) << 16);
  *reinterpret_cast<uint2*>(W1b + w * FDIM + f) = p;
  float4 a4 = *reinterpret_cast<const float4*>(as_att + f);
  float4 d4 = *reinterpret_cast<const float4*>(ad_att + f);
  float ps = fmaf(v.x, a4.x, fmaf(v.y, a4.y, fmaf(v.z, a4.z, v.w * a4.w)));
  float pd = fmaf(v.x, d4.x, fmaf(v.y, d4.y, fmaf(v.z, d4.z, v.w * d4.w)));
#pragma unroll
  for (int o = 1; o < 16; o <<= 1){ ps += __shfl_xor(ps, o, 64); pd += __shfl_xor(pd, o, 64); }
  if ((lane & 15) == 0){
    int hh = lane >> 4;
    als[w * 4 + hh] = ps;
    ald[w * 4 + hh] = pd;
  }
}

// ---------------- W2 transpose-to-bf16 + edge dst counting (merged) -----------
__global__ void k_misc(const float* __restrict__ W2, unsigned short* __restrict__ W2t,
                       const int* __restrict__ ei, int* __restrict__ cnt){
  int i = blockIdx.x * blockDim.x + threadIdx.x;
  if (i < 65536){
    int j = i >> 8, k = i & 255;
    W2t[i] = f2bf(W2[k * 256 + j]);
  }
  if (i < EP){
    int dst = (i < EE) ? ei[EE + i] : (i - EE);
    atomicAdd(&cnt[dst], 1);
  }
}

// ---------------- CSR scan + scatter ----------------
__global__ __launch_bounds__(1024) void k_scan(const int* __restrict__ cnt,
                                               int* __restrict__ row_ptr){
  __shared__ int part[1024];
  int t = threadIdx.x;
  int v[8]; int s = 0;
#pragma unroll
  for (int j = 0; j < 8; ++j){ v[j] = cnt[t * 8 + j]; s += v[j]; }
  part[t] = s;
  __syncthreads();
  for (int off = 1; off < 1024; off <<= 1){
    int x = (t >= off) ? part[t - off] : 0;
    __syncthreads();
    part[t] += x;
    __syncthreads();
  }
  int base = (t == 0) ? 0 : part[t - 1];
#pragma unroll
  for (int j = 0; j < 8; ++j){ row_ptr[t * 8 + j] = base; base += v[j]; }
  if (t == 1023) row_ptr[8192] = base;
}

__global__ void k_scatter(const int* __restrict__ ei, const int* __restrict__ row_ptr,
                          int* __restrict__ cur, int* __restrict__ csr_src){
  int i = blockIdx.x * blockDim.x + threadIdx.x;
  if (i >= EP) return;
  int src, dst;
  if (i < EE){ src = ei[i]; dst = ei[EE + i]; } else { src = dst = i - EE; }
  int pos = row_ptr[dst] + atomicAdd(&cur[dst], 1);
  csr_src[pos] = src;
}

// ---------------- attention logits from bf16 features (layer 2) ---------------
__global__ void k_al_b(const unsigned short* __restrict__ hb, const float* __restrict__ as_att,
                       const float* __restrict__ ad_att, float* __restrict__ als,
                       float* __restrict__ ald){
  int w = (blockIdx.x * blockDim.x + threadIdx.x) >> 6;   // node
  int lane = threadIdx.x & 63;
  int f = lane << 2;
  bf16x4 hv = *reinterpret_cast<const bf16x4*>(hb + w * FDIM + f);
  float4 as4 = *reinterpret_cast<const float4*>(as_att + f);
  float4 ad4 = *reinterpret_cast<const float4*>(ad_att + f);
  float x0 = bf2f(hv[0]), x1 = bf2f(hv[1]), x2 = bf2f(hv[2]), x3 = bf2f(hv[3]);
  float ps = fmaf(x0, as4.x, fmaf(x1, as4.y, fmaf(x2, as4.z, x3 * as4.w)));
  float pd = fmaf(x0, ad4.x, fmaf(x1, ad4.y, fmaf(x2, ad4.z, x3 * ad4.w)));
#pragma unroll
  for (int o = 1; o < 16; o <<= 1){ ps += __shfl_xor(ps, o, 64); pd += __shfl_xor(pd, o, 64); }
  if ((lane & 15) == 0){
    int hh = lane >> 4;
    als[w * 4 + hh] = ps;
    ald[w * 4 + hh] = pd;
  }
}

// ------- fused softmax + aggregation: wave per node (all 4 heads) -------------
// L1: out = bf16(relu(agg + b1)) -> outb
// L2: z = tanh(mean_heads(agg) + b2) -> zout (f32) + zb (bf16)
template <bool L1>
__global__ __launch_bounds__(256) void k_smagg(const unsigned short* __restrict__ hb,
                                               const float* __restrict__ als,
                                               const float* __restrict__ ald,
                                               const int* __restrict__ row_ptr,
                                               const int* __restrict__ csr_src,
                                               const float* __restrict__ bias,
                                               unsigned short* __restrict__ outb,
                                               float* __restrict__ zout,
                                               unsigned short* __restrict__ zb){
  __shared__ float pbuf[4][1024];          // per wave: 256 edges x 4 heads
  int wid = threadIdx.x >> 6, lane = threadIdx.x & 63;
  int n = blockIdx.x * 4 + wid;
  int b0 = row_ptr[n], e0 = row_ptr[n + 1];
  int deg = e0 - b0;
  float4 ad4 = *reinterpret_cast<const float4*>(ald + n * 4);

  // phase A: per-edge exp numerators (lanes over edges) + denominator
  float4 den4 = {0.f, 0.f, 0.f, 0.f};
  for (int j = b0 + lane; j < e0; j += 64){
    int s = csr_src[j];
    float4 av = *reinterpret_cast<const float4*>(als + s * 4);
    float e; float4 pv;
    e = av.x + ad4.x; e = e > 0.f ? e : 0.2f * e; pv.x = __expf(e);
    e = av.y + ad4.y; e = e > 0.f ? e : 0.2f * e; pv.y = __expf(e);
    e = av.z + ad4.z; e = e > 0.f ? e : 0.2f * e; pv.z = __expf(e);
    e = av.w + ad4.w; e = e > 0.f ? e : 0.2f * e; pv.w = __expf(e);
    int idx = j - b0;
    if (idx < 256) *reinterpret_cast<float4*>(&pbuf[wid][idx * 4]) = pv;
    den4.x += pv.x; den4.y += pv.y; den4.z += pv.z; den4.w += pv.w;
  }
#pragma unroll
  for (int o = 32; o; o >>= 1){
    den4.x += __shfl_xor(den4.x, o, 64);
    den4.y += __shfl_xor(den4.y, o, 64);
    den4.z += __shfl_xor(den4.z, o, 64);
    den4.w += __shfl_xor(den4.w, o, 64);
  }
  __syncthreads();

  // phase B: weighted feature gather (lanes over features)
  int hh = lane >> 4;
  int f = lane << 2;
  float den_h = hh == 0 ? den4.x : hh == 1 ? den4.y : hh == 2 ? den4.z : den4.w;
  float ad_h  = hh == 0 ? ad4.x  : hh == 1 ? ad4.y  : hh == 2 ? ad4.z  : ad4.w;
  float r = 1.f / (den_h + 1e-16f);
  float a0 = 0.f, a1 = 0.f, a2 = 0.f, a3 = 0.f;
  const unsigned short* hp = hb + f;
  if (deg <= 256){
#pragma unroll 4
    for (int c = b0; c < e0; ++c){
      int s = csr_src[c];                          // uniform within wave
      float a = pbuf[wid][(c - b0) * 4 + hh];
      bf16x4 hv = *reinterpret_cast<const bf16x4*>(hp + s * FDIM);
      a0 = fmaf(a, bf2f(hv[0]), a0);
      a1 = fmaf(a, bf2f(hv[1]), a1);
      a2 = fmaf(a, bf2f(hv[2]), a2);
      a3 = fmaf(a, bf2f(hv[3]), a3);
    }
  } else {                                         // rare fallback: recompute
    for (int c = b0; c < e0; ++c){
      int s = csr_src[c];
      float ev = als[s * 4 + hh] + ad_h;
      ev = ev > 0.f ? ev : 0.2f * ev;
      float a = __expf(ev);
      bf16x4 hv = *reinterpret_cast<const bf16x4*>(hp + s * FDIM);
      a0 = fmaf(a, bf2f(hv[0]), a0);
      a1 = fmaf(a, bf2f(hv[1]), a1);
      a2 = fmaf(a, bf2f(hv[2]), a2);
      a3 = fmaf(a, bf2f(hv[3]), a3);
    }
  }

  if (L1){
    float4 bv = *reinterpret_cast<const float4*>(bias + f);
    float o0 = fmaxf(fmaf(a0, r, bv.x), 0.f);
    float o1 = fmaxf(fmaf(a1, r, bv.y), 0.f);
    float o2 = fmaxf(fmaf(a2, r, bv.z), 0.f);
    float o3 = fmaxf(fmaf(a3, r, bv.w), 0.f);
    uint2 p;
    p.x = (unsigned)f2bf(o0) | ((unsigned)f2bf(o1) << 16);
    p.y = (unsigned)f2bf(o2) | ((unsigned)f2bf(o3) << 16);
    *reinterpret_cast<uint2*>(outb + n * FDIM + f) = p;
  } else {
    // fused z: mean over heads + b2 + tanh
    float s0 = a0 * r, s1 = a1 * r, s2 = a2 * r, s3 = a3 * r;
    s0 += __shfl_xor(s0, 16, 64); s0 += __shfl_xor(s0, 32, 64);
    s1 += __shfl_xor(s1, 16, 64); s1 += __shfl_xor(s1, 32, 64);
    s2 += __shfl_xor(s2, 16, 64); s2 += __shfl_xor(s2, 32, 64);
    s3 += __shfl_xor(s3, 16, 64); s3 += __shfl_xor(s3, 32, 64);
    if (lane < 16){
      int j0 = lane * 4;
      float4 bv = *reinterpret_cast<const float4*>(bias + j0);
      float v0 = tanhf(fmaf(0.25f, s0, bv.x));
      float v1 = tanhf(fmaf(0.25f, s1, bv.y));
      float v2 = tanhf(fmaf(0.25f, s2, bv.z));
      float v3 = tanhf(fmaf(0.25f, s3, bv.w));
      float4 zv; zv.x = v0; zv.y = v1; zv.z = v2; zv.w = v3;
      *reinterpret_cast<float4*>(zout + n * 64 + j0) = zv;
      uint2 p;
      p.x = (unsigned)f2bf(v0) | ((unsigned)f2bf(v1) << 16);
      p.y = (unsigned)f2bf(v2) | ((unsigned)f2bf(v3) << 16);
      *reinterpret_cast<uint2*>(zb + n * 64 + j0) = p;
    }
  }
}

// ---------------- h2 = hrelu @ W2 via bf16 MFMA ----------------
__global__ __launch_bounds__(256) void k_gemm2(const unsigned short* __restrict__ A,
                                               const unsigned short* __restrict__ Bt,
                                               unsigned short* __restrict__ Cb){
  int wid = threadIdx.x >> 6, lane = threadIdx.x & 63;
  int row0 = blockIdx.x * 128 + wid * 32;
  int col0 = blockIdx.y * 64;
  int r = lane & 31, half = lane >> 5;
  f32x16 acc0, acc1;
#pragma unroll
  for (int t = 0; t < 16; ++t){ acc0[t] = 0.f; acc1[t] = 0.f; }
#pragma unroll
  for (int k0 = 0; k0 < 256; k0 += 16){
    bf16x8 av  = *reinterpret_cast<const bf16x8*>(A  + (row0 + r)      * 256 + k0 + 8 * half);
    bf16x8 b0v = *reinterpret_cast<const bf16x8*>(Bt + (col0 + r)      * 256 + k0 + 8 * half);
    bf16x8 b1v = *reinterpret_cast<const bf16x8*>(Bt + (col0 + 32 + r) * 256 + k0 + 8 * half);
    acc0 = __builtin_amdgcn_mfma_f32_32x32x16_bf16(av, b0v, acc0, 0, 0, 0);
    acc1 = __builtin_amdgcn_mfma_f32_32x32x16_bf16(av, b1v, acc1, 0, 0, 0);
  }
#pragma unroll
  for (int t = 0; t < 16; ++t){
    int rr = (t & 3) + 8 * (t >> 2) + 4 * half;
    Cb[(row0 + rr) * 256 + col0 + r]      = f2bf(acc0[t]);
    Cb[(row0 + rr) * 256 + col0 + 32 + r] = f2bf(acc1[t]);
  }
}

// ---------------- adj = sigmoid(z z^T) via bf16 MFMA ----------------
__global__ __launch_bounds__(256) void k_adj(const unsigned short* __restrict__ zb,
                                             float* __restrict__ adj){
  int wid = threadIdx.x >> 6, lane = threadIdx.x & 63;
  int wr = wid >> 1, wc = wid & 1;           // 2x2 waves, each 64x64 tile
  int row0 = blockIdx.y * 128 + wr * 64;
  int col0 = blockIdx.x * 128 + wc * 64;
  int r = lane & 31, half = lane >> 5;

  bf16x8 a[2][4], b[2][4];
#pragma unroll
  for (int i = 0; i < 2; ++i)
#pragma unroll
    for (int kc = 0; kc < 4; ++kc){
      a[i][kc] = *reinterpret_cast<const bf16x8*>(zb + (size_t)(row0 + 32 * i + r) * 64 + kc * 16 + 8 * half);
      b[i][kc] = *reinterpret_cast<const bf16x8*>(zb + (size_t)(col0 + 32 * i + r) * 64 + kc * 16 + 8 * half);
    }

  f32x16 c[2][2];
#pragma unroll
  for (int i = 0; i < 2; ++i)
#pragma unroll
    for (int j = 0; j < 2; ++j)
#pragma unroll
      for (int t = 0; t < 16; ++t) c[i][j][t] = 0.f;

#pragma unroll
  for (int kc = 0; kc < 4; ++kc)
#pragma unroll
    for (int i = 0; i < 2; ++i)
#pragma unroll
      for (int j = 0; j < 2; ++j)
        c[i][j] = __builtin_amdgcn_mfma_f32_32x32x16_bf16(a[i][kc], b[j][kc], c[i][j], 0, 0, 0);

#pragma unroll
  for (int i = 0; i < 2; ++i)
#pragma unroll
    for (int j = 0; j < 2; ++j)
#pragma unroll
      for (int t = 0; t < 16; ++t){
        int rr = (t & 3) + 8 * (t >> 2) + 4 * half;
        size_t row = row0 + 32 * i + rr;
        size_t col = col0 + 32 * j + (lane & 31);
        float v = c[i][j][t];
        adj[row * NN + col] = __builtin_amdgcn_rcpf(1.0f + __expf(-v));
      }
}

extern "C" void kernel_launch(void* const* d_in, const int* in_sizes, int n_in,
                              void* d_out, int out_size, void* d_ws, size_t ws_size,
                              hipStream_t stream){
  (void)in_sizes; (void)n_in; (void)out_size; (void)ws_size;
  const int*   ei  = (const int*)d_in[1];
  const float* W1  = (const float*)d_in[2];
  const float* as1 = (const float*)d_in[3];
  const float* ad1 = (const float*)d_in[4];
  const float* b1  = (const float*)d_in[5];
  const float* W2  = (const float*)d_in[6];
  const float* as2 = (const float*)d_in[7];
  const float* ad2 = (const float*)d_in[8];
  const float* b2  = (const float*)d_in[9];

  char* ws = (char*)d_ws;
  unsigned short* W1b    = (unsigned short*)(ws + 0);            // 4 MB
  unsigned short* hrelub = (unsigned short*)(ws + (4u  << 20));  // 4 MB
  unsigned short* h2b    = (unsigned short*)(ws + (8u  << 20));  // 4 MB
  unsigned short* W2t    = (unsigned short*)(ws + (12u << 20));  // 128 KB
  float* als1            = (float*)(ws + (13u << 20));
  float* ald1            = als1 + NN * 4;
  float* als2            = ald1 + NN * 4;
  float* ald2            = als2 + NN * 4;
  int* cnt               = (int*)(ws + (14u << 20));
  int* cur               = cnt + 16384;
  int* row_ptr           = cur + 16384;
  int* csr_src           = row_ptr + 16384;                      // 1.06 MB
  unsigned short* zb     = (unsigned short*)(ws + (16u << 20));  // 1 MB

  float* adj  = (float*)d_out;
  float* zout = adj + (size_t)NN * NN;

  hipMemsetAsync(cnt, 0, 2 * 16384 * sizeof(int), stream);
  k_cvt_al<<<NN / 4, 256, 0, stream>>>(W1, as1, ad1, W1b, als1, ald1);
  k_misc<<<(EP + 255) / 256, 256, 0, stream>>>(W2, W2t, ei, cnt);
  k_scan<<<1, 1024, 0, stream>>>(cnt, row_ptr);
  k_scatter<<<(EP + 255) / 256, 256, 0, stream>>>(ei, row_ptr, cur, csr_src);

  // layer 1 (h1 = W1 because x == I)
  k_smagg<true><<<NN / 4, 256, 0, stream>>>(W1b, als1, ald1, row_ptr, csr_src, b1,
                                            hrelub, nullptr, nullptr);

  // layer 2
  dim3 gg(NN / 128, 4);
  k_gemm2<<<gg, 256, 0, stream>>>(hrelub, W2t, h2b);
  k_al_b<<<NN / 4, 256, 0, stream>>>(h2b, as2, ad2, als2, ald2);
  k_smagg<false><<<NN / 4, 256, 0, stream>>>(h2b, als2, ald2, row_ptr, csr_src, b2,
                                             nullptr, zout, zb);

  // adjacency reconstruction
  dim3 g(NN / 128, NN / 128);
  k_adj<<<g, 256, 0, stream>>>(zb, adj);
}